// Round 21
// baseline (128.892 us; speedup 1.0000x reference)
//
#include <hip/hip_runtime.h>
#include <math.h>

#define BB 8
#define NN 1024
#define HH 256
#define ALPHAC 0.25f

typedef short bf16x8 __attribute__((ext_vector_type(8)));
typedef unsigned short u16x8 __attribute__((ext_vector_type(8)));
typedef float f32x4 __attribute__((ext_vector_type(4)));

__device__ inline unsigned short f2bf(float x) {
  unsigned u = __builtin_bit_cast(unsigned, x);
  unsigned r = (u + 0x7fffu + ((u >> 16) & 1u)) >> 16;
  return (unsigned short)r;
}
__device__ inline float bf2f(unsigned short u) {
  return __builtin_bit_cast(float, (unsigned)u << 16);
}

// symmetric permutation 0 <-> 1023 (det-invariant)
__device__ inline int prm(int i) { return i == 0 ? 1023 : (i == 1023 ? 0 : i); }

// ---------------- workspace layout (float-slot offsets) ----------------
static const size_t OFF_TMPBF = 0;          // tmp_bf [8192][512] bf16 (2M slots)
static const size_t OFF_HBF   = 2097152;    // h_bf   [8192][256] bf16 (1M)
static const size_t OFF_BT    = 3145728;    // BT     [768][256]  bf16 (98304) -> 3244032
static const size_t OFF_EL    = 3244040;    // par    [8192] uint
static const size_t OFF_EV    = 3252240;    // edgeval[8192] f32
static const size_t OFF_R1    = 3260448;    // r1pre  [8192][256] bf16 (1M slots)
static const size_t OFF_M     = 4325376;    // M [8][1024][1024] bf16 (4M slots)
static const size_t OFF_SM    = 8519680;
static const size_t O_H0 = 0, O_H1 = 8192, O_D0 = 16384, O_D1 = 24576, O_RS = 32768;
static const size_t O_GOLD = 40960, O_SLOG = 40968, O_NEG = 40976, O_ZER = 40984;
static const size_t O_CS   = 40992;         // colsum [8][1024] f32

// ---------------- KA: fused h-cast + head/dep dots + weight casts + parent extract ----------------
__global__ __launch_bounds__(256) void kA_pre(const float* __restrict__ h_cat,
    const float* __restrict__ Wb, const float* __restrict__ Wr1,
    const float* __restrict__ W_head, const float* __restrict__ W_dep,
    const float* __restrict__ left, const float* __restrict__ right,
    unsigned short* __restrict__ h_bf, unsigned short* __restrict__ BT,
    float* __restrict__ head0, float* __restrict__ head1,
    float* __restrict__ dep0, float* __restrict__ dep1,
    unsigned* __restrict__ par) {
  int bid = blockIdx.x, tid = threadIdx.x;
  if (bid < 2048) {
    int wave = tid >> 6, lane = tid & 63;
    int row = bid * 4 + wave;
    float4 h4 = *(const float4*)&h_cat[(size_t)row * 256 + lane * 4];
    ushort4 o;
    o.x = f2bf(h4.x); o.y = f2bf(h4.y); o.z = f2bf(h4.z); o.w = f2bf(h4.w);
    *(ushort4*)&h_bf[(size_t)row * 256 + lane * 4] = o;
    float4 wh0 = *(const float4*)&W_head[lane * 4];
    float4 wh1 = *(const float4*)&W_head[256 + lane * 4];
    float4 wd0 = *(const float4*)&W_dep[lane * 4];
    float4 wd1 = *(const float4*)&W_dep[256 + lane * 4];
    float s0 = h4.x * wh0.x + h4.y * wh0.y + h4.z * wh0.z + h4.w * wh0.w;
    float s1 = h4.x * wh1.x + h4.y * wh1.y + h4.z * wh1.z + h4.w * wh1.w;
    float s2 = h4.x * wd0.x + h4.y * wd0.y + h4.z * wd0.z + h4.w * wd0.w;
    float s3 = h4.x * wd1.x + h4.y * wd1.y + h4.z * wd1.z + h4.w * wd1.w;
#pragma unroll
    for (int off = 32; off; off >>= 1) {
      s0 += __shfl_down(s0, off);
      s1 += __shfl_down(s1, off);
      s2 += __shfl_down(s2, off);
      s3 += __shfl_down(s3, off);
    }
    if (lane == 0) {
      head0[row] = s0; head1[row] = s1; dep0[row] = s2; dep1[row] = s3;
    }
  } else if (bid < 2560) {
    int idx = (bid - 2048) * 256 + tid;
    int c = idx >> 8, h = idx & 255;
    BT[(size_t)c * 256 + h] = f2bf(Wb[(size_t)(c >> 8) * 65536 + (size_t)h * 256 + (c & 255)]);
  } else if (bid < 2816) {
    int idx = (bid - 2560) * 256 + tid;
    int c = idx >> 8, h = idx & 255;
    BT[(size_t)(512 + c) * 256 + h] = f2bf(Wr1[(size_t)c * 256 + h]);
  } else {
    int base = (bid - 2816) * 256 + tid;     // [0, 1048576)
#pragma unroll
    for (int it = 0; it < 2; ++it) {
      int g = base + it * 1048576;
      float4 v = *(const float4*)&left[(size_t)g * 4];
      if (v.x != 0.f || v.y != 0.f || v.z != 0.f || v.w != 0.f) {
        float va[4] = {v.x, v.y, v.z, v.w};
#pragma unroll
        for (int c = 0; c < 4; ++c)
          if (va[c] != 0.f) {
            int e = g * 4 + c;
            par[((e >> 20) << 10) | (e & 1023)] = (unsigned)((e >> 10) & 1023);
          }
      }
      float4 u = *(const float4*)&right[(size_t)g * 4];
      if (u.x != 0.f || u.y != 0.f || u.z != 0.f || u.w != 0.f) {
        float ua[4] = {u.x, u.y, u.z, u.w};
#pragma unroll
        for (int c = 0; c < 4; ++c)
          if (ua[c] != 0.f) {
            int e = g * 4 + c;
            par[((e >> 20) << 10) | (e & 1023)] = 0x80000000u | (unsigned)((e >> 10) & 1023);
          }
      }
    }
  }
}

// ---------------- KF: fused tmp + r1pre + biaffine compat -> M + colsum ----------------
// 256 blocks (b = bid&7 XCD pin; it = 32-row i-tile, 0..31), 1024 threads (16 waves).
// Each block computes its tmp tile ONCE and both j-halves (no phase-1 duplication).
// 50KB LDS -> 2 blocks/CU possible (8 waves/SIMD).
__global__ __launch_bounds__(1024) void kF(const unsigned short* __restrict__ h_bf,
    const unsigned short* __restrict__ BT, const float* __restrict__ b_bilin,
    const float* __restrict__ head0, const float* __restrict__ head1,
    const float* __restrict__ dep0, const float* __restrict__ dep1,
    unsigned short* __restrict__ tmp_bf, unsigned short* __restrict__ r1pre,
    unsigned short* __restrict__ M, float* __restrict__ colsum) {
  __shared__ __align__(16) unsigned short tmpS[32][520];   // 33280 B
  __shared__ __align__(16) unsigned short hA[32][264];     // 16896 B
  int tid = threadIdx.x;
  int lane = tid & 63, w = tid >> 6;           // w in [0,16)
  int fr = lane & 15, kof = (lane >> 4) * 8;
  int bid = blockIdx.x;
  int b = bid & 7;
  int it = bid >> 3;                           // 0..31
  int i0 = it * 32;
  size_t bN = (size_t)b * NN;
  // ---- stage A-tile (32 rows of h): 1024 u16x8 groups ----
  {
    int r = tid >> 5, c8 = (tid & 31) * 8;
    *(u16x8*)&hA[r][c8] = *(const u16x8*)&h_bf[(bN + i0 + r) * 256 + c8];
  }
  __syncthreads();
  // ---- phase 1: tmp tile cols w*32..+32 (A from LDS, B from L2) ----
  {
    int c0 = w * 32;
    f32x4 acc[2][2] = {};
#pragma unroll
    for (int k = 0; k < 8; ++k) {
      bf16x8 a[2], bb[2];
#pragma unroll
      for (int rt = 0; rt < 2; ++rt)
        a[rt] = *(const bf16x8*)&hA[rt * 16 + fr][k * 32 + kof];
#pragma unroll
      for (int ct = 0; ct < 2; ++ct)
        bb[ct] = *(const bf16x8*)&BT[(size_t)(c0 + ct * 16 + fr) * 256 + k * 32 + kof];
#pragma unroll
      for (int rt = 0; rt < 2; ++rt)
#pragma unroll
        for (int ct = 0; ct < 2; ++ct)
          acc[rt][ct] = __builtin_amdgcn_mfma_f32_16x16x32_bf16(a[rt], bb[ct], acc[rt][ct], 0, 0, 0);
    }
#pragma unroll
    for (int rt = 0; rt < 2; ++rt)
#pragma unroll
      for (int ct = 0; ct < 2; ++ct)
#pragma unroll
        for (int q = 0; q < 4; ++q)
          tmpS[rt * 16 + (lane >> 4) * 4 + q][c0 + ct * 16 + fr] = f2bf(acc[rt][ct][q]);
  }
  // ---- r1pre tile: wave w -> cols w*16..+16, straight to global ----
  {
    f32x4 accr[2] = {};
#pragma unroll
    for (int k = 0; k < 8; ++k) {
      bf16x8 br = *(const bf16x8*)&BT[(size_t)(512 + w * 16 + fr) * 256 + k * 32 + kof];
#pragma unroll
      for (int rt = 0; rt < 2; ++rt) {
        bf16x8 a = *(const bf16x8*)&hA[rt * 16 + fr][k * 32 + kof];
        accr[rt] = __builtin_amdgcn_mfma_f32_16x16x32_bf16(a, br, accr[rt], 0, 0, 0);
      }
    }
#pragma unroll
    for (int rt = 0; rt < 2; ++rt)
#pragma unroll
      for (int q = 0; q < 4; ++q)
        r1pre[(bN + i0 + rt * 16 + (lane >> 4) * 4 + q) * 256 + w * 16 + fr] = f2bf(accr[rt][q]);
  }
  __syncthreads();
  // ---- tmp tile -> global (consumed by kGold): 2048 u16x8 groups ----
#pragma unroll
  for (int itc = 0; itc < 2; ++itc) {
    int g = tid + itc * 1024;
    int r = g >> 6, c8 = (g & 63) * 8;
    *(u16x8*)&tmp_bf[(bN + i0 + r) * 512 + c8] = *(const u16x8*)&tmpS[r][c8];
  }
  // ---- phase 2: wave w -> strips w*32 (half 0) and 512+w*32 (half 1) ----
  f32x4 acc0[2][2][2] = {}, acc1[2][2][2] = {};   // [half][rt][ct]
#pragma unroll
  for (int k = 0; k < 8; ++k) {
    bf16x8 bfr[2][2];
#pragma unroll
    for (int hf = 0; hf < 2; ++hf)
#pragma unroll
      for (int ct = 0; ct < 2; ++ct)
        bfr[hf][ct] = *(const bf16x8*)&h_bf[(bN + hf * 512 + w * 32 + ct * 16 + fr) * 256 + k * 32 + kof];
#pragma unroll
    for (int rt = 0; rt < 2; ++rt) {
      bf16x8 a0 = *(const bf16x8*)&tmpS[rt * 16 + fr][k * 32 + kof];
      bf16x8 a1 = *(const bf16x8*)&tmpS[rt * 16 + fr][256 + k * 32 + kof];
#pragma unroll
      for (int hf = 0; hf < 2; ++hf)
#pragma unroll
        for (int ct = 0; ct < 2; ++ct) {
          acc0[hf][rt][ct] = __builtin_amdgcn_mfma_f32_16x16x32_bf16(a0, bfr[hf][ct], acc0[hf][rt][ct], 0, 0, 0);
          acc1[hf][rt][ct] = __builtin_amdgcn_mfma_f32_16x16x32_bf16(a1, bfr[hf][ct], acc1[hf][rt][ct], 0, 0, 0);
        }
    }
  }
  // ---- epilogue: exp + colsum, per half; stage into tmpS and store ----
  float bb0 = b_bilin[0], bb1 = b_bilin[1];
  size_t Mb = (size_t)b * NN * NN;
  unsigned short outv[2][2][2][4];   // [half][rt][ct][q]
#pragma unroll
  for (int hf = 0; hf < 2; ++hf) {
    float d0a[2], d1a[2];
#pragma unroll
    for (int ct = 0; ct < 2; ++ct) {
      int j = hf * 512 + w * 32 + ct * 16 + fr;
      d0a[ct] = dep0[bN + j];
      d1a[ct] = dep1[bN + j];
    }
    float csum[2] = {};
#pragma unroll
    for (int rt = 0; rt < 2; ++rt)
#pragma unroll
      for (int q = 0; q < 4; ++q) {
        int i = i0 + rt * 16 + (lane >> 4) * 4 + q;
        float h0 = head0[bN + i], h1 = head1[bN + i];
#pragma unroll
        for (int ct = 0; ct < 2; ++ct) {
          float c0 = acc0[hf][rt][ct][q] + h0 + d0a[ct] + bb0;
          float c1 = acc1[hf][rt][ct][q] + h1 + d1a[ct] + bb1;
          float aexp = __expf(c0) + __expf(c1);
          csum[ct] += aexp;
          outv[hf][rt][ct][q] = f2bf(-aexp);
        }
      }
#pragma unroll
    for (int ct = 0; ct < 2; ++ct) {
      float v = csum[ct];
      v += __shfl_down(v, 32);
      v += __shfl_down(v, 16);
      if (lane < 16) atomicAdd(&colsum[bN + prm(hf * 512 + w * 32 + ct * 16 + lane)], v);
    }
  }
  // store halves through tmpS (vectorized permuted-row stores)
#pragma unroll
  for (int hf = 0; hf < 2; ++hf) {
    __syncthreads();           // tmpS free (phase2 reads / prior half's stores done)
#pragma unroll
    for (int rt = 0; rt < 2; ++rt)
#pragma unroll
      for (int ct = 0; ct < 2; ++ct)
#pragma unroll
        for (int q = 0; q < 4; ++q)
          tmpS[rt * 16 + (lane >> 4) * 4 + q][w * 32 + ct * 16 + fr] = outv[hf][rt][ct][q];
    __syncthreads();
#pragma unroll
    for (int itc = 0; itc < 2; ++itc) {
      int g = tid + itc * 1024;              // 2048 u16x8 groups (32x512)
      int r = g >> 6, c8 = (g & 63) * 8;
      int pi = prm(i0 + r);
      int j8 = hf * 512 + c8;
      if ((hf == 0 && c8 == 0) || (hf == 1 && c8 == 504)) {
#pragma unroll
        for (int u = 0; u < 8; ++u)
          M[Mb + (size_t)pi * NN + prm(j8 + u)] = tmpS[r][c8 + u];
      } else {
        *(u16x8*)&M[Mb + (size_t)pi * NN + j8] = *(const u16x8*)&tmpS[r][c8];
      }
    }
  }
}

// ---------------- KB: fused kGold + k1c (root scores) ----------------
__global__ __launch_bounds__(256) void kB_post(const unsigned* __restrict__ par,
    const unsigned short* __restrict__ tmp_bf, const unsigned short* __restrict__ h_bf,
    const float* __restrict__ head0, const float* __restrict__ head1,
    const float* __restrict__ dep0, const float* __restrict__ dep1,
    const float* __restrict__ b_bilin, const unsigned short* __restrict__ r1pre,
    const float* __restrict__ b_r1, const float* __restrict__ W_r2,
    const float* __restrict__ b_r2, float* __restrict__ edgeval,
    float* __restrict__ rs) {
  int bid = blockIdx.x, tid = threadIdx.x;
  int w = tid >> 6, lane = tid & 63;
  if (bid < 2046) {
    int ei = bid * 4 + w;
    if (ei >= 8184) return;
    int b = ei / 1023;
    int j = ei - b * 1023 + 1;
    unsigned p = par[(b << 10) + j];
    int s = (int)(p >> 31);
    int i = (int)(p & 1023u);
    const unsigned short* tp = tmp_bf + (size_t)(b * NN + i) * 512 + s * 256 + lane * 4;
    const unsigned short* hp = h_bf + (size_t)(b * NN + j) * 256 + lane * 4;
    ushort4 tv = *(const ushort4*)tp;
    ushort4 hv = *(const ushort4*)hp;
    float dot = bf2f(tv.x) * bf2f(hv.x) + bf2f(tv.y) * bf2f(hv.y) +
                bf2f(tv.z) * bf2f(hv.z) + bf2f(tv.w) * bf2f(hv.w);
#pragma unroll
    for (int off = 32; off; off >>= 1) dot += __shfl_down(dot, off);
    if (lane == 0)
      edgeval[ei] = dot + (s ? head1 : head0)[b * NN + i] + (s ? dep1 : dep0)[b * NN + j] + b_bilin[s];
  } else if (bid < 4094) {
    int row = (bid - 2046) * 4 + w;
    ushort4 r4 = *(const ushort4*)&r1pre[(size_t)row * 256 + lane * 4];
    float4 br4 = *(const float4*)&b_r1[lane * 4];
    float4 wr2 = *(const float4*)&W_r2[lane * 4];
    float xa = bf2f(r4.x) + br4.x, xb = bf2f(r4.y) + br4.y;
    float xc = bf2f(r4.z) + br4.z, xd = bf2f(r4.w) + br4.w;
    float ga = 0.5f * xa * (1.0f + erff(xa * 0.70710678118654752f));
    float gb = 0.5f * xb * (1.0f + erff(xb * 0.70710678118654752f));
    float gc = 0.5f * xc * (1.0f + erff(xc * 0.70710678118654752f));
    float gd = 0.5f * xd * (1.0f + erff(xd * 0.70710678118654752f));
    float s4 = ga * wr2.x + gb * wr2.y + gc * wr2.z + gd * wr2.w;
#pragma unroll
    for (int off = 32; off; off >>= 1) s4 += __shfl_down(s4, off);
    if (lane == 0) rs[row] = s4 + b_r2[0];
  }
}

// ---------------- K3b: diag += colsum; permuted row 1023 = exp(root_scores) ----------------
__global__ __launch_bounds__(1024) void k3b_diag(unsigned short* __restrict__ M,
    const float* __restrict__ colsum, const float* __restrict__ rs) {
  int j = threadIdx.x;
  int b = blockIdx.x;
  unsigned short* Mb = M + (size_t)b * NN * NN;
  float d = bf2f(Mb[(size_t)j * NN + j]) + colsum[b * NN + j];
  if (j != 1023) Mb[(size_t)j * NN + j] = f2bf(d);
  Mb[(size_t)1023 * NN + j] = f2bf(expf(rs[b * NN + prm(j)]));
}

// ---------------- K6: NB=256 Schur step, 64x128 C tiles ----------------
#define AS(r, c) sb[(r) * 72 + (c)]
#define CSS(r, c) sb[(r) * 136 + (c)]
__global__ __launch_bounds__(256) void k6_schur256(unsigned short* __restrict__ M, int k0,
    int nt_c, float* __restrict__ slog, int* __restrict__ negc, int* __restrict__ zerc) {
  __shared__ __align__(16) unsigned short sb[4608 + 128 * 72];   // 27648 B
  __shared__ float rd[256];
  int tid = threadIdx.x;
  int bid = blockIdx.x;
  int b = bid & 7;
  int n = bid >> 3;
  int by = n / nt_c, bx = n - by * nt_c;
  unsigned short* Mb = M + (size_t)b * NN * NN;
  {
    float d = bf2f(Mb[(size_t)(k0 + tid) * NN + k0 + tid]);
    rd[tid] = 1.0f / d;
    if (n == 0) {
      float lf = logf(fabsf(d));
      int flg = (d < 0.f ? 1 : 0) + (d == 0.f ? (1 << 16) : 0);
#pragma unroll
      for (int off = 32; off; off >>= 1) { lf += __shfl_down(lf, off); flg += __shfl_down(flg, off); }
      if ((tid & 63) == 0) { atomicAdd(&slog[b], lf); atomicAdd(&negc[b], flg & 0xffff); atomicAdd(&zerc[b], flg >> 16); }
    }
  }
  int i0 = k0 + 256 + by * 64;
  int j0 = k0 + 256 + bx * 128;
  int lane = tid & 63, w = tid >> 6;
  int rb = w * 16, fr = lane & 15, kof = (lane >> 4) * 8, cb = lane & 15;
  f32x4 acc[8] = {};
#pragma unroll
  for (int kc = 0; kc < 4; ++kc) {
    __syncthreads();
#pragma unroll
    for (int it = 0; it < 4; ++it) {
      int g = tid + it * 256;
      if (it < 2) {                             // A: 64x64 chunk, 512 groups
        int r = g >> 3, c = (g & 7) * 8;
        u16x8 vv = *(const u16x8*)&Mb[(size_t)(i0 + r) * NN + k0 + kc * 64 + c];
        u16x8 ov;
#pragma unroll
        for (int u = 0; u < 8; ++u) ov[u] = f2bf(bf2f(vv[u]) * rd[kc * 64 + c + u]);
        *(u16x8*)&AS(r, c) = ov;
      }
      int r2 = g >> 4, c2 = (g & 15) * 8;       // Bt: 64k x 128j, 1024 groups
      u16x8 uu = *(const u16x8*)&Mb[(size_t)(k0 + kc * 64 + r2) * NN + j0 + c2];
#pragma unroll
      for (int u = 0; u < 8; ++u) {
        int col = c2 + u;
        sb[4608 + col * 72 + ((((r2 >> 3) ^ ((col >> 3) & 7)) << 3) | (r2 & 7))] = uu[u];
      }
    }
    __syncthreads();
#pragma unroll
    for (int ks = 0; ks < 2; ++ks) {
      bf16x8 a = *(const bf16x8*)&AS(rb + fr, ks * 32 + kof);
      int G = (ks * 32 + kof) >> 3;
#pragma unroll
      for (int t = 0; t < 8; ++t) {
        int R = t * 16 + fr;
        bf16x8 bb = *(const bf16x8*)&sb[4608 + R * 72 + ((G ^ ((R >> 3) & 7)) << 3)];
        acc[t] = __builtin_amdgcn_mfma_f32_16x16x32_bf16(a, bb, acc[t], 0, 0, 0);
      }
    }
  }
  __syncthreads();
  {
    int rr = rb + (lane >> 4) * 4;
#pragma unroll
    for (int t = 0; t < 8; ++t)
#pragma unroll
      for (int q = 0; q < 4; ++q) CSS(rr + q, t * 16 + cb) = f2bf(acc[t][q]);
  }
  __syncthreads();
#pragma unroll
  for (int it = 0; it < 4; ++it) {
    int g = it * 256 + tid;                     // 1024 u16x8 groups (64x128)
    int r = g >> 4, c8 = (g & 15) * 8;
    unsigned short* gp = &Mb[(size_t)(i0 + r) * NN + j0 + c8];
    u16x8 old = *(const u16x8*)gp;
    u16x8 del = *(const u16x8*)&CSS(r, c8);
    u16x8 out;
#pragma unroll
    for (int u = 0; u < 8; ++u) out[u] = f2bf(bf2f(old[u]) - bf2f(del[u]));
    *(u16x8*)gp = out;
  }
}

// ---------------- K9: fused final 256x256 tail ----------------
__global__ __launch_bounds__(1024) void k9_final(const unsigned short* __restrict__ M,
    float* __restrict__ slog, int* __restrict__ negc, int* __restrict__ zerc) {
  __shared__ __align__(16) unsigned short As[128][136];
  __shared__ __align__(16) unsigned short Bt[128 * 136];
  __shared__ float Cs[128][132];
  __shared__ float rdv[128];
  __shared__ float wsum[16];
  __shared__ int wflg[16];
  int b = blockIdx.x, tid = threadIdx.x;
  int lane = tid & 63, w = tid >> 6;
  const unsigned short* Mb = M + (size_t)b * NN * NN;
  float lfacc = 0.f; int flacc = 0;
  if (tid < 128) {
    float d = bf2f(Mb[(size_t)(768 + tid) * NN + 768 + tid]);
    rdv[tid] = 1.0f / d;
    lfacc += logf(fabsf(d));
    flacc += (d < 0.f ? 1 : 0) + (d == 0.f ? (1 << 16) : 0);
  }
  __syncthreads();
#pragma unroll
  for (int it = 0; it < 2; ++it) {
    int g = tid + it * 1024;
    int r = g >> 4, c8 = (g & 15) * 8;
    u16x8 vv = *(const u16x8*)&Mb[(size_t)(896 + r) * NN + 768 + c8];
    u16x8 ov;
#pragma unroll
    for (int u = 0; u < 8; ++u) ov[u] = f2bf(bf2f(vv[u]) * rdv[c8 + u]);
    *(u16x8*)&As[r][c8] = ov;
    u16x8 uu = *(const u16x8*)&Mb[(size_t)(768 + r) * NN + 896 + c8];
    int X = ((r >> 3) ^ (c8 >> 3)) & 15;
    int pb = c8 * 136 + X * 8 + (r & 7);
#pragma unroll
    for (int u = 0; u < 8; ++u) Bt[pb + u * 136] = uu[u];
    u16x8 cc = *(const u16x8*)&Mb[(size_t)(896 + r) * NN + 896 + c8];
#pragma unroll
    for (int u = 0; u < 8; ++u) Cs[r][c8 + u] = bf2f(cc[u]);
  }
  __syncthreads();
  {
    int tr = w >> 1, cg = w & 1;
    int rb = tr * 16, fr = lane & 15, kof = (lane >> 4) * 8, cb = lane & 15;
    f32x4 acc[4] = {};
#pragma unroll
    for (int kc = 0; kc < 4; ++kc) {
      bf16x8 a = *(const bf16x8*)&As[rb + fr][kof + kc * 32];
      int K8 = (kc * 32 + kof) >> 3;
#pragma unroll
      for (int t = 0; t < 4; ++t) {
        int c = cg * 64 + t * 16 + fr;
        bf16x8 bb = *(const bf16x8*)&Bt[c * 136 + ((K8 ^ ((c >> 3) & 15)) << 3)];
        acc[t] = __builtin_amdgcn_mfma_f32_16x16x32_bf16(a, bb, acc[t], 0, 0, 0);
      }
    }
#pragma unroll
    for (int t = 0; t < 4; ++t)
#pragma unroll
      for (int q = 0; q < 4; ++q)
        Cs[rb + (lane >> 4) * 4 + q][cg * 64 + t * 16 + cb] -= acc[t][q];
  }
  __syncthreads();
  if (tid < 64) {
    float d = Cs[tid][tid];
    rdv[tid] = 1.0f / d;
    lfacc += logf(fabsf(d));
    flacc += (d < 0.f ? 1 : 0) + (d == 0.f ? (1 << 16) : 0);
  }
  __syncthreads();
  {
    int ty = tid >> 5, tx = tid & 31;
    float acc[2][2] = {};
    for (int k = 0; k < 64; ++k) {
      float ik = rdv[k];
      float a0 = Cs[64 + ty * 2 + 0][k] * ik;
      float a1 = Cs[64 + ty * 2 + 1][k] * ik;
      float b0 = Cs[k][64 + tx * 2 + 0];
      float b1 = Cs[k][64 + tx * 2 + 1];
      acc[0][0] += a0 * b0; acc[0][1] += a0 * b1;
      acc[1][0] += a1 * b0; acc[1][1] += a1 * b1;
    }
#pragma unroll
    for (int r = 0; r < 2; ++r)
#pragma unroll
      for (int c = 0; c < 2; ++c)
        Cs[64 + ty * 2 + r][64 + tx * 2 + c] -= acc[r][c];
  }
  __syncthreads();
  if (tid < 32) {
    float d = Cs[64 + tid][64 + tid];
    rdv[tid] = 1.0f / d;
    lfacc += logf(fabsf(d));
    flacc += (d < 0.f ? 1 : 0) + (d == 0.f ? (1 << 16) : 0);
  }
  __syncthreads();
  {
    int r = tid >> 5, c = tid & 31;
    float acc = 0.f;
    for (int k = 0; k < 32; ++k)
      acc += Cs[96 + r][64 + k] * rdv[k] * Cs[64 + k][96 + c];
    Cs[96 + r][96 + c] -= acc;
  }
  __syncthreads();
  {
    int r5 = tid >> 3, c4 = (tid & 7) * 4;
    for (int j = 0; j < 31; ++j) {
      if (tid < 256 && r5 > j) {
        float inv = 1.0f / Cs[96 + j][96 + j];
        float lrj = Cs[96 + r5][96 + j] * inv;
#pragma unroll
        for (int u = 0; u < 4; ++u) {
          int c = c4 + u;
          if (c > j) Cs[96 + r5][96 + c] -= lrj * Cs[96 + j][96 + c];
        }
      }
      __syncthreads();
    }
    if (tid < 32) {
      float d = Cs[96 + tid][96 + tid];
      lfacc += logf(fabsf(d));
      flacc += (d < 0.f ? 1 : 0) + (d == 0.f ? (1 << 16) : 0);
    }
  }
#pragma unroll
  for (int off = 32; off; off >>= 1) { lfacc += __shfl_down(lfacc, off); flacc += __shfl_down(flacc, off); }
  if (lane == 0) { wsum[w] = lfacc; wflg[w] = flacc; }
  __syncthreads();
  if (tid == 0) {
    float lf = 0.f; int fl = 0;
#pragma unroll
    for (int i = 0; i < 16; ++i) { lf += wsum[i]; fl += wflg[i]; }
    atomicAdd(&slog[b], lf);
    atomicAdd(&negc[b], fl & 0xffff);
    atomicAdd(&zerc[b], fl >> 16);
  }
}

// ---------------- K7: edge reduce + final loss (one 512-thread block) ----------------
__global__ __launch_bounds__(512) void k7_final(const float* __restrict__ edgeval,
    const float* __restrict__ rs, const int* __restrict__ roots,
    const float* __restrict__ slog, const int* __restrict__ negc,
    const int* __restrict__ zerc, float* __restrict__ out) {
  __shared__ float gld[8];
  int w = threadIdx.x >> 6, lane = threadIdx.x & 63;
  float s = 0.f;
  for (int e = lane; e < 1023; e += 64) s += edgeval[w * 1023 + e];
#pragma unroll
  for (int off = 32; off; off >>= 1) s += __shfl_down(s, off);
  if (lane == 0) gld[w] = s;
  __syncthreads();
  if (threadIdx.x == 0) {
    float acc = 0.f;
    for (int b = 0; b < BB; ++b) {
      int root = roots[b];
      float gold = rs[b * NN + root] + gld[b];
      float ld = slog[b];
      bool pos = ((negc[b] & 1) == 0) && (zerc[b] == 0);
      float loss = 0.f;
      if (pos && !isnan(ld) && !isnan(gold)) {
        if (gold <= ld) loss = ld - gold;
      }
      if (isnan(loss) || isinf(loss)) loss = 0.f;
      acc += loss;
    }
    out[0] = ALPHAC * acc / (float)BB;
  }
}

extern "C" void kernel_launch(void* const* d_in, const int* in_sizes, int n_in,
                              void* d_out, int out_size, void* d_ws, size_t ws_size,
                              hipStream_t stream) {
  (void)in_sizes; (void)n_in; (void)out_size; (void)ws_size;
  const float* h_cat  = (const float*)d_in[0];
  const float* left   = (const float*)d_in[1];
  const float* right  = (const float*)d_in[2];
  const int*   roots  = (const int*)d_in[3];
  const float* W_bilin = (const float*)d_in[4];
  const float* b_bilin = (const float*)d_in[5];
  const float* W_head = (const float*)d_in[6];
  const float* W_dep  = (const float*)d_in[7];
  const float* W_r1   = (const float*)d_in[8];
  const float* b_r1   = (const float*)d_in[9];
  const float* W_r2   = (const float*)d_in[10];
  const float* b_r2   = (const float*)d_in[11];

  float* ws = (float*)d_ws;
  unsigned short* tmp_bf = (unsigned short*)(ws + OFF_TMPBF);
  unsigned short* h_bf   = (unsigned short*)(ws + OFF_HBF);
  unsigned short* BT     = (unsigned short*)(ws + OFF_BT);
  unsigned* par  = (unsigned*)(ws + OFF_EL);
  float* edgeval = ws + OFF_EV;
  unsigned short* r1pre  = (unsigned short*)(ws + OFF_R1);
  unsigned short* M = (unsigned short*)(ws + OFF_M);
  float* sm    = ws + OFF_SM;
  float* head0 = sm + O_H0;
  float* head1 = sm + O_H1;
  float* dep0  = sm + O_D0;
  float* dep1  = sm + O_D1;
  float* rs    = sm + O_RS;
  float* gold  = sm + O_GOLD;
  float* slog  = sm + O_SLOG;
  int*   negc  = (int*)(sm + O_NEG);
  int*   zerc  = (int*)(sm + O_ZER);
  float* colsum = sm + O_CS;

  hipMemsetAsync(gold, 0, (32 + BB * NN) * sizeof(float), stream); // gold/slog/negc/zerc/colsum

  kA_pre<<<6912, 256, 0, stream>>>(h_cat, W_bilin, W_r1, W_head, W_dep, left, right,
                                   h_bf, BT, head0, head1, dep0, dep1, par);
  kF<<<256, 1024, 0, stream>>>(h_bf, BT, b_bilin, head0, head1, dep0, dep1,
                               tmp_bf, r1pre, M, colsum);
  kB_post<<<4094, 256, 0, stream>>>(par, tmp_bf, h_bf, head0, head1, dep0, dep1,
                                    b_bilin, r1pre, b_r1, W_r2, b_r2, edgeval, rs);
  k3b_diag<<<8, 1024, 0, stream>>>(M, colsum, rs);
  for (int s = 0; s < 3; ++s) {
    int k0 = s * 256;
    int rem = 1024 - 256 - k0;
    int nt_r = rem / 64, nt_c = rem / 128;
    k6_schur256<<<nt_r * nt_c * 8, 256, 0, stream>>>(M, k0, nt_c, slog, negc, zerc);
  }
  k9_final<<<8, 1024, 0, stream>>>(M, slog, negc, zerc);
  k7_final<<<1, 512, 0, stream>>>(edgeval, rs, roots, slog, negc, zerc, (float*)d_out);
}

// Round 22
// 122.759 us; speedup vs baseline: 1.0500x; 1.0500x over previous
//
#include <hip/hip_runtime.h>
#include <math.h>

#define BB 8
#define NN 1024
#define HH 256
#define ALPHAC 0.25f

typedef short bf16x8 __attribute__((ext_vector_type(8)));
typedef unsigned short u16x8 __attribute__((ext_vector_type(8)));
typedef float f32x4 __attribute__((ext_vector_type(4)));

__device__ inline unsigned short f2bf(float x) {
  unsigned u = __builtin_bit_cast(unsigned, x);
  unsigned r = (u + 0x7fffu + ((u >> 16) & 1u)) >> 16;
  return (unsigned short)r;
}
__device__ inline float bf2f(unsigned short u) {
  return __builtin_bit_cast(float, (unsigned)u << 16);
}

// symmetric permutation 0 <-> 1023 (det-invariant)
__device__ inline int prm(int i) { return i == 0 ? 1023 : (i == 1023 ? 0 : i); }

// ---------------- workspace layout (float-slot offsets) ----------------
static const size_t OFF_TMPBF = 0;          // tmp_bf [8192][512] bf16 (2M slots)
static const size_t OFF_HBF   = 2097152;    // h_bf   [8192][256] bf16 (1M)
static const size_t OFF_BT    = 3145728;    // BT     [768][256]  bf16 (98304) -> 3244032
static const size_t OFF_EL    = 3244040;    // par    [8192] uint
static const size_t OFF_EV    = 3252240;    // edgeval[8192] f32
static const size_t OFF_R1    = 3260448;    // r1pre  [8192][256] bf16 (1M slots)
static const size_t OFF_M     = 4325376;    // M [8][1024][1024] bf16 (4M slots)
static const size_t OFF_SM    = 8519680;
static const size_t O_H0 = 0, O_H1 = 8192, O_D0 = 16384, O_D1 = 24576, O_RS = 32768;
static const size_t O_GOLD = 40960, O_SLOG = 40968, O_NEG = 40976, O_ZER = 40984;
static const size_t O_CS   = 40992;         // colsum [8][1024] f32

// ---------------- KA: fused h-cast + head/dep dots + weight casts + parent extract ----------------
__global__ __launch_bounds__(256) void kA_pre(const float* __restrict__ h_cat,
    const float* __restrict__ Wb, const float* __restrict__ Wr1,
    const float* __restrict__ W_head, const float* __restrict__ W_dep,
    const float* __restrict__ left, const float* __restrict__ right,
    unsigned short* __restrict__ h_bf, unsigned short* __restrict__ BT,
    float* __restrict__ head0, float* __restrict__ head1,
    float* __restrict__ dep0, float* __restrict__ dep1,
    unsigned* __restrict__ par) {
  int bid = blockIdx.x, tid = threadIdx.x;
  if (bid < 2048) {
    int wave = tid >> 6, lane = tid & 63;
    int row = bid * 4 + wave;
    float4 h4 = *(const float4*)&h_cat[(size_t)row * 256 + lane * 4];
    ushort4 o;
    o.x = f2bf(h4.x); o.y = f2bf(h4.y); o.z = f2bf(h4.z); o.w = f2bf(h4.w);
    *(ushort4*)&h_bf[(size_t)row * 256 + lane * 4] = o;
    float4 wh0 = *(const float4*)&W_head[lane * 4];
    float4 wh1 = *(const float4*)&W_head[256 + lane * 4];
    float4 wd0 = *(const float4*)&W_dep[lane * 4];
    float4 wd1 = *(const float4*)&W_dep[256 + lane * 4];
    float s0 = h4.x * wh0.x + h4.y * wh0.y + h4.z * wh0.z + h4.w * wh0.w;
    float s1 = h4.x * wh1.x + h4.y * wh1.y + h4.z * wh1.z + h4.w * wh1.w;
    float s2 = h4.x * wd0.x + h4.y * wd0.y + h4.z * wd0.z + h4.w * wd0.w;
    float s3 = h4.x * wd1.x + h4.y * wd1.y + h4.z * wd1.z + h4.w * wd1.w;
#pragma unroll
    for (int off = 32; off; off >>= 1) {
      s0 += __shfl_down(s0, off);
      s1 += __shfl_down(s1, off);
      s2 += __shfl_down(s2, off);
      s3 += __shfl_down(s3, off);
    }
    if (lane == 0) {
      head0[row] = s0; head1[row] = s1; dep0[row] = s2; dep1[row] = s3;
    }
  } else if (bid < 2560) {
    int idx = (bid - 2048) * 256 + tid;
    int c = idx >> 8, h = idx & 255;
    BT[(size_t)c * 256 + h] = f2bf(Wb[(size_t)(c >> 8) * 65536 + (size_t)h * 256 + (c & 255)]);
  } else if (bid < 2816) {
    int idx = (bid - 2560) * 256 + tid;
    int c = idx >> 8, h = idx & 255;
    BT[(size_t)(512 + c) * 256 + h] = f2bf(Wr1[(size_t)c * 256 + h]);
  } else {
    int base = (bid - 2816) * 256 + tid;     // [0, 1048576)
#pragma unroll
    for (int it = 0; it < 2; ++it) {
      int g = base + it * 1048576;
      float4 v = *(const float4*)&left[(size_t)g * 4];
      if (v.x != 0.f || v.y != 0.f || v.z != 0.f || v.w != 0.f) {
        float va[4] = {v.x, v.y, v.z, v.w};
#pragma unroll
        for (int c = 0; c < 4; ++c)
          if (va[c] != 0.f) {
            int e = g * 4 + c;
            par[((e >> 20) << 10) | (e & 1023)] = (unsigned)((e >> 10) & 1023);
          }
      }
      float4 u = *(const float4*)&right[(size_t)g * 4];
      if (u.x != 0.f || u.y != 0.f || u.z != 0.f || u.w != 0.f) {
        float ua[4] = {u.x, u.y, u.z, u.w};
#pragma unroll
        for (int c = 0; c < 4; ++c)
          if (ua[c] != 0.f) {
            int e = g * 4 + c;
            par[((e >> 20) << 10) | (e & 1023)] = 0x80000000u | (unsigned)((e >> 10) & 1023);
          }
      }
    }
  }
}

// ---------------- KF: fused tmp + r1pre + biaffine compat -> M + colsum ----------------
// 256 blocks (b = bid&7 XCD pin; it = 64-row i-tile; jh = j-half), 1024 threads
// (16 waves, each owns a 32-col j-strip).
__global__ __launch_bounds__(1024) void kF(const unsigned short* __restrict__ h_bf,
    const unsigned short* __restrict__ BT, const float* __restrict__ b_bilin,
    const float* __restrict__ head0, const float* __restrict__ head1,
    const float* __restrict__ dep0, const float* __restrict__ dep1,
    unsigned short* __restrict__ tmp_bf, unsigned short* __restrict__ r1pre,
    unsigned short* __restrict__ M, float* __restrict__ colsum) {
  __shared__ __align__(16) unsigned short tmpS[64][520];   // 66560 B
  __shared__ __align__(16) unsigned short hA[64][264];     // 33792 B
  int tid = threadIdx.x;
  int lane = tid & 63, w = tid >> 6;           // w in [0,16)
  int fr = lane & 15, kof = (lane >> 4) * 8;
  int bid = blockIdx.x;
  int b = bid & 7;
  int n = bid >> 3;
  int it = n >> 1, jh = n & 1;
  int i0 = it * 64;
  size_t bN = (size_t)b * NN;
  // ---- stage A-tile (64 rows of h) ----
#pragma unroll
  for (int s = 0; s < 2; ++s) {
    int g = tid + s * 1024;                    // 2048 u16x8 groups
    int r = g >> 5, c8 = (g & 31) * 8;
    *(u16x8*)&hA[r][c8] = *(const u16x8*)&h_bf[(bN + i0 + r) * 256 + c8];
  }
  __syncthreads();
  // ---- phase 1: tmp tile cols w*32..+32 (A from LDS, B from L2) ----
  {
    int c0 = w * 32;
    f32x4 acc[4][2] = {};
#pragma unroll
    for (int k = 0; k < 8; ++k) {
      bf16x8 a[4], bb[2];
#pragma unroll
      for (int rt = 0; rt < 4; ++rt)
        a[rt] = *(const bf16x8*)&hA[rt * 16 + fr][k * 32 + kof];
#pragma unroll
      for (int ct = 0; ct < 2; ++ct)
        bb[ct] = *(const bf16x8*)&BT[(size_t)(c0 + ct * 16 + fr) * 256 + k * 32 + kof];
#pragma unroll
      for (int rt = 0; rt < 4; ++rt)
#pragma unroll
        for (int ct = 0; ct < 2; ++ct)
          acc[rt][ct] = __builtin_amdgcn_mfma_f32_16x16x32_bf16(a[rt], bb[ct], acc[rt][ct], 0, 0, 0);
    }
#pragma unroll
    for (int rt = 0; rt < 4; ++rt)
#pragma unroll
      for (int ct = 0; ct < 2; ++ct)
#pragma unroll
        for (int q = 0; q < 4; ++q)
          tmpS[rt * 16 + (lane >> 4) * 4 + q][c0 + ct * 16 + fr] = f2bf(acc[rt][ct][q]);
  }
  // ---- r1pre tile (jh==0 only): wave w -> cols w*16..+16, straight to global ----
  if (jh == 0) {
    f32x4 accr[4] = {};
#pragma unroll
    for (int k = 0; k < 8; ++k) {
      bf16x8 br = *(const bf16x8*)&BT[(size_t)(512 + w * 16 + fr) * 256 + k * 32 + kof];
#pragma unroll
      for (int rt = 0; rt < 4; ++rt) {
        bf16x8 a = *(const bf16x8*)&hA[rt * 16 + fr][k * 32 + kof];
        accr[rt] = __builtin_amdgcn_mfma_f32_16x16x32_bf16(a, br, accr[rt], 0, 0, 0);
      }
    }
#pragma unroll
    for (int rt = 0; rt < 4; ++rt)
#pragma unroll
      for (int q = 0; q < 4; ++q)
        r1pre[(bN + i0 + rt * 16 + (lane >> 4) * 4 + q) * 256 + w * 16 + fr] = f2bf(accr[rt][q]);
  }
  __syncthreads();
  // ---- tmp tile -> global (jh==0 only; consumed by kGold) ----
  if (jh == 0) {
#pragma unroll
    for (int itc = 0; itc < 4; ++itc) {
      int g = tid + itc * 1024;                // 4096 u16x8 groups
      int r = g >> 6, c8 = (g & 63) * 8;
      *(u16x8*)&tmp_bf[(bN + i0 + r) * 512 + c8] = *(const u16x8*)&tmpS[r][c8];
    }
  }
  // ---- phase 2: wave w -> j-strip at j0 (64 rows x 32 cols x 2 channels) ----
  int j0 = jh * 512 + w * 32;
  f32x4 acc0[4][2] = {}, acc1[4][2] = {};
#pragma unroll
  for (int k = 0; k < 8; ++k) {
    bf16x8 bfr[2];
#pragma unroll
    for (int ct = 0; ct < 2; ++ct)
      bfr[ct] = *(const bf16x8*)&h_bf[(bN + j0 + ct * 16 + fr) * 256 + k * 32 + kof];
#pragma unroll
    for (int rt = 0; rt < 4; ++rt) {
      bf16x8 a0 = *(const bf16x8*)&tmpS[rt * 16 + fr][k * 32 + kof];
      bf16x8 a1 = *(const bf16x8*)&tmpS[rt * 16 + fr][256 + k * 32 + kof];
#pragma unroll
      for (int ct = 0; ct < 2; ++ct) {
        acc0[rt][ct] = __builtin_amdgcn_mfma_f32_16x16x32_bf16(a0, bfr[ct], acc0[rt][ct], 0, 0, 0);
        acc1[rt][ct] = __builtin_amdgcn_mfma_f32_16x16x32_bf16(a1, bfr[ct], acc1[rt][ct], 0, 0, 0);
      }
    }
  }
  // ---- epilogue: exp + colsum (values kept in regs) ----
  float bb0 = b_bilin[0], bb1 = b_bilin[1];
  float d0a[2], d1a[2];
#pragma unroll
  for (int ct = 0; ct < 2; ++ct) {
    int j = j0 + ct * 16 + fr;
    d0a[ct] = dep0[bN + j];
    d1a[ct] = dep1[bN + j];
  }
  unsigned short outv[4][2][4];
  float csum[2] = {};
#pragma unroll
  for (int rt = 0; rt < 4; ++rt)
#pragma unroll
    for (int q = 0; q < 4; ++q) {
      int i = i0 + rt * 16 + (lane >> 4) * 4 + q;
      float h0 = head0[bN + i], h1 = head1[bN + i];
#pragma unroll
      for (int ct = 0; ct < 2; ++ct) {
        float c0 = acc0[rt][ct][q] + h0 + d0a[ct] + bb0;
        float c1 = acc1[rt][ct][q] + h1 + d1a[ct] + bb1;
        float aexp = __expf(c0) + __expf(c1);
        csum[ct] += aexp;
        outv[rt][ct][q] = f2bf(-aexp);
      }
    }
#pragma unroll
  for (int ct = 0; ct < 2; ++ct) {
    float v = csum[ct];
    v += __shfl_down(v, 32);
    v += __shfl_down(v, 16);
    if (lane < 16) atomicAdd(&colsum[bN + prm(j0 + ct * 16 + lane)], v);
  }
  __syncthreads();          // all waves done reading tmpS
  // ---- stage M tile into tmpS (wave w owns cols w*32..+32) ----
#pragma unroll
  for (int rt = 0; rt < 4; ++rt)
#pragma unroll
    for (int ct = 0; ct < 2; ++ct)
#pragma unroll
      for (int q = 0; q < 4; ++q)
        tmpS[rt * 16 + (lane >> 4) * 4 + q][w * 32 + ct * 16 + fr] = outv[rt][ct][q];
  __syncthreads();
  // ---- vectorized global M store (permuted rows; scalar only at permuted cols) ----
  size_t Mb = (size_t)b * NN * NN;
#pragma unroll
  for (int itc = 0; itc < 4; ++itc) {
    int g = tid + itc * 1024;                // 4096 u16x8 groups
    int r = g >> 6, c8 = (g & 63) * 8;
    int pi = prm(i0 + r);
    int j8 = jh * 512 + c8;
    if ((jh == 0 && c8 == 0) || (jh == 1 && c8 == 504)) {
#pragma unroll
      for (int u = 0; u < 8; ++u)
        M[Mb + (size_t)pi * NN + prm(j8 + u)] = tmpS[r][c8 + u];
    } else {
      *(u16x8*)&M[Mb + (size_t)pi * NN + j8] = *(const u16x8*)&tmpS[r][c8];
    }
  }
}

// ---------------- KB: fused kGold + k1c (root scores) ----------------
__global__ __launch_bounds__(256) void kB_post(const unsigned* __restrict__ par,
    const unsigned short* __restrict__ tmp_bf, const unsigned short* __restrict__ h_bf,
    const float* __restrict__ head0, const float* __restrict__ head1,
    const float* __restrict__ dep0, const float* __restrict__ dep1,
    const float* __restrict__ b_bilin, const unsigned short* __restrict__ r1pre,
    const float* __restrict__ b_r1, const float* __restrict__ W_r2,
    const float* __restrict__ b_r2, float* __restrict__ edgeval,
    float* __restrict__ rs) {
  int bid = blockIdx.x, tid = threadIdx.x;
  int w = tid >> 6, lane = tid & 63;
  if (bid < 2046) {
    int ei = bid * 4 + w;
    if (ei >= 8184) return;
    int b = ei / 1023;
    int j = ei - b * 1023 + 1;
    unsigned p = par[(b << 10) + j];
    int s = (int)(p >> 31);
    int i = (int)(p & 1023u);
    const unsigned short* tp = tmp_bf + (size_t)(b * NN + i) * 512 + s * 256 + lane * 4;
    const unsigned short* hp = h_bf + (size_t)(b * NN + j) * 256 + lane * 4;
    ushort4 tv = *(const ushort4*)tp;
    ushort4 hv = *(const ushort4*)hp;
    float dot = bf2f(tv.x) * bf2f(hv.x) + bf2f(tv.y) * bf2f(hv.y) +
                bf2f(tv.z) * bf2f(hv.z) + bf2f(tv.w) * bf2f(hv.w);
#pragma unroll
    for (int off = 32; off; off >>= 1) dot += __shfl_down(dot, off);
    if (lane == 0)
      edgeval[ei] = dot + (s ? head1 : head0)[b * NN + i] + (s ? dep1 : dep0)[b * NN + j] + b_bilin[s];
  } else if (bid < 4094) {
    int row = (bid - 2046) * 4 + w;
    ushort4 r4 = *(const ushort4*)&r1pre[(size_t)row * 256 + lane * 4];
    float4 br4 = *(const float4*)&b_r1[lane * 4];
    float4 wr2 = *(const float4*)&W_r2[lane * 4];
    float xa = bf2f(r4.x) + br4.x, xb = bf2f(r4.y) + br4.y;
    float xc = bf2f(r4.z) + br4.z, xd = bf2f(r4.w) + br4.w;
    float ga = 0.5f * xa * (1.0f + erff(xa * 0.70710678118654752f));
    float gb = 0.5f * xb * (1.0f + erff(xb * 0.70710678118654752f));
    float gc = 0.5f * xc * (1.0f + erff(xc * 0.70710678118654752f));
    float gd = 0.5f * xd * (1.0f + erff(xd * 0.70710678118654752f));
    float s4 = ga * wr2.x + gb * wr2.y + gc * wr2.z + gd * wr2.w;
#pragma unroll
    for (int off = 32; off; off >>= 1) s4 += __shfl_down(s4, off);
    if (lane == 0) rs[row] = s4 + b_r2[0];
  }
}

// ---------------- K3b: diag += colsum; permuted row 1023 = exp(root_scores) ----------------
__global__ __launch_bounds__(1024) void k3b_diag(unsigned short* __restrict__ M,
    const float* __restrict__ colsum, const float* __restrict__ rs) {
  int j = threadIdx.x;
  int b = blockIdx.x;
  unsigned short* Mb = M + (size_t)b * NN * NN;
  float d = bf2f(Mb[(size_t)j * NN + j]) + colsum[b * NN + j];
  if (j != 1023) Mb[(size_t)j * NN + j] = f2bf(d);
  Mb[(size_t)1023 * NN + j] = f2bf(expf(rs[b * NN + prm(j)]));
}

// ---------------- K6: NB=256 Schur step, 64x128 C tiles ----------------
#define AS(r, c) sb[(r) * 72 + (c)]
#define CSS(r, c) sb[(r) * 136 + (c)]
__global__ __launch_bounds__(256) void k6_schur256(unsigned short* __restrict__ M, int k0,
    int nt_c, float* __restrict__ slog, int* __restrict__ negc, int* __restrict__ zerc) {
  __shared__ __align__(16) unsigned short sb[4608 + 128 * 72];   // 27648 B
  __shared__ float rd[256];
  int tid = threadIdx.x;
  int bid = blockIdx.x;
  int b = bid & 7;
  int n = bid >> 3;
  int by = n / nt_c, bx = n - by * nt_c;
  unsigned short* Mb = M + (size_t)b * NN * NN;
  {
    float d = bf2f(Mb[(size_t)(k0 + tid) * NN + k0 + tid]);
    rd[tid] = 1.0f / d;
    if (n == 0) {
      float lf = logf(fabsf(d));
      int flg = (d < 0.f ? 1 : 0) + (d == 0.f ? (1 << 16) : 0);
#pragma unroll
      for (int off = 32; off; off >>= 1) { lf += __shfl_down(lf, off); flg += __shfl_down(flg, off); }
      if ((tid & 63) == 0) { atomicAdd(&slog[b], lf); atomicAdd(&negc[b], flg & 0xffff); atomicAdd(&zerc[b], flg >> 16); }
    }
  }
  int i0 = k0 + 256 + by * 64;
  int j0 = k0 + 256 + bx * 128;
  int lane = tid & 63, w = tid >> 6;
  int rb = w * 16, fr = lane & 15, kof = (lane >> 4) * 8, cb = lane & 15;
  f32x4 acc[8] = {};
#pragma unroll
  for (int kc = 0; kc < 4; ++kc) {
    __syncthreads();
#pragma unroll
    for (int it = 0; it < 4; ++it) {
      int g = tid + it * 256;
      if (it < 2) {                             // A: 64x64 chunk, 512 groups
        int r = g >> 3, c = (g & 7) * 8;
        u16x8 vv = *(const u16x8*)&Mb[(size_t)(i0 + r) * NN + k0 + kc * 64 + c];
        u16x8 ov;
#pragma unroll
        for (int u = 0; u < 8; ++u) ov[u] = f2bf(bf2f(vv[u]) * rd[kc * 64 + c + u]);
        *(u16x8*)&AS(r, c) = ov;
      }
      int r2 = g >> 4, c2 = (g & 15) * 8;       // Bt: 64k x 128j, 1024 groups
      u16x8 uu = *(const u16x8*)&Mb[(size_t)(k0 + kc * 64 + r2) * NN + j0 + c2];
#pragma unroll
      for (int u = 0; u < 8; ++u) {
        int col = c2 + u;
        sb[4608 + col * 72 + ((((r2 >> 3) ^ ((col >> 3) & 7)) << 3) | (r2 & 7))] = uu[u];
      }
    }
    __syncthreads();
#pragma unroll
    for (int ks = 0; ks < 2; ++ks) {
      bf16x8 a = *(const bf16x8*)&AS(rb + fr, ks * 32 + kof);
      int G = (ks * 32 + kof) >> 3;
#pragma unroll
      for (int t = 0; t < 8; ++t) {
        int R = t * 16 + fr;
        bf16x8 bb = *(const bf16x8*)&sb[4608 + R * 72 + ((G ^ ((R >> 3) & 7)) << 3)];
        acc[t] = __builtin_amdgcn_mfma_f32_16x16x32_bf16(a, bb, acc[t], 0, 0, 0);
      }
    }
  }
  __syncthreads();
  {
    int rr = rb + (lane >> 4) * 4;
#pragma unroll
    for (int t = 0; t < 8; ++t)
#pragma unroll
      for (int q = 0; q < 4; ++q) CSS(rr + q, t * 16 + cb) = f2bf(acc[t][q]);
  }
  __syncthreads();
#pragma unroll
  for (int it = 0; it < 4; ++it) {
    int g = it * 256 + tid;                     // 1024 u16x8 groups (64x128)
    int r = g >> 4, c8 = (g & 15) * 8;
    unsigned short* gp = &Mb[(size_t)(i0 + r) * NN + j0 + c8];
    u16x8 old = *(const u16x8*)gp;
    u16x8 del = *(const u16x8*)&CSS(r, c8);
    u16x8 out;
#pragma unroll
    for (int u = 0; u < 8; ++u) out[u] = f2bf(bf2f(old[u]) - bf2f(del[u]));
    *(u16x8*)gp = out;
  }
}

// ---------------- K9: fused final 256x256 tail ----------------
__global__ __launch_bounds__(1024) void k9_final(const unsigned short* __restrict__ M,
    float* __restrict__ slog, int* __restrict__ negc, int* __restrict__ zerc) {
  __shared__ __align__(16) unsigned short As[128][136];
  __shared__ __align__(16) unsigned short Bt[128 * 136];
  __shared__ float Cs[128][132];
  __shared__ float rdv[128];
  __shared__ float wsum[16];
  __shared__ int wflg[16];
  int b = blockIdx.x, tid = threadIdx.x;
  int lane = tid & 63, w = tid >> 6;
  const unsigned short* Mb = M + (size_t)b * NN * NN;
  float lfacc = 0.f; int flacc = 0;
  if (tid < 128) {
    float d = bf2f(Mb[(size_t)(768 + tid) * NN + 768 + tid]);
    rdv[tid] = 1.0f / d;
    lfacc += logf(fabsf(d));
    flacc += (d < 0.f ? 1 : 0) + (d == 0.f ? (1 << 16) : 0);
  }
  __syncthreads();
#pragma unroll
  for (int it = 0; it < 2; ++it) {
    int g = tid + it * 1024;
    int r = g >> 4, c8 = (g & 15) * 8;
    u16x8 vv = *(const u16x8*)&Mb[(size_t)(896 + r) * NN + 768 + c8];
    u16x8 ov;
#pragma unroll
    for (int u = 0; u < 8; ++u) ov[u] = f2bf(bf2f(vv[u]) * rdv[c8 + u]);
    *(u16x8*)&As[r][c8] = ov;
    u16x8 uu = *(const u16x8*)&Mb[(size_t)(768 + r) * NN + 896 + c8];
    int X = ((r >> 3) ^ (c8 >> 3)) & 15;
    int pb = c8 * 136 + X * 8 + (r & 7);
#pragma unroll
    for (int u = 0; u < 8; ++u) Bt[pb + u * 136] = uu[u];
    u16x8 cc = *(const u16x8*)&Mb[(size_t)(896 + r) * NN + 896 + c8];
#pragma unroll
    for (int u = 0; u < 8; ++u) Cs[r][c8 + u] = bf2f(cc[u]);
  }
  __syncthreads();
  {
    int tr = w >> 1, cg = w & 1;
    int rb = tr * 16, fr = lane & 15, kof = (lane >> 4) * 8, cb = lane & 15;
    f32x4 acc[4] = {};
#pragma unroll
    for (int kc = 0; kc < 4; ++kc) {
      bf16x8 a = *(const bf16x8*)&As[rb + fr][kof + kc * 32];
      int K8 = (kc * 32 + kof) >> 3;
#pragma unroll
      for (int t = 0; t < 4; ++t) {
        int c = cg * 64 + t * 16 + fr;
        bf16x8 bb = *(const bf16x8*)&Bt[c * 136 + ((K8 ^ ((c >> 3) & 15)) << 3)];
        acc[t] = __builtin_amdgcn_mfma_f32_16x16x32_bf16(a, bb, acc[t], 0, 0, 0);
      }
    }
#pragma unroll
    for (int t = 0; t < 4; ++t)
#pragma unroll
      for (int q = 0; q < 4; ++q)
        Cs[rb + (lane >> 4) * 4 + q][cg * 64 + t * 16 + cb] -= acc[t][q];
  }
  __syncthreads();
  if (tid < 64) {
    float d = Cs[tid][tid];
    rdv[tid] = 1.0f / d;
    lfacc += logf(fabsf(d));
    flacc += (d < 0.f ? 1 : 0) + (d == 0.f ? (1 << 16) : 0);
  }
  __syncthreads();
  {
    int ty = tid >> 5, tx = tid & 31;
    float acc[2][2] = {};
    for (int k = 0; k < 64; ++k) {
      float ik = rdv[k];
      float a0 = Cs[64 + ty * 2 + 0][k] * ik;
      float a1 = Cs[64 + ty * 2 + 1][k] * ik;
      float b0 = Cs[k][64 + tx * 2 + 0];
      float b1 = Cs[k][64 + tx * 2 + 1];
      acc[0][0] += a0 * b0; acc[0][1] += a0 * b1;
      acc[1][0] += a1 * b0; acc[1][1] += a1 * b1;
    }
#pragma unroll
    for (int r = 0; r < 2; ++r)
#pragma unroll
      for (int c = 0; c < 2; ++c)
        Cs[64 + ty * 2 + r][64 + tx * 2 + c] -= acc[r][c];
  }
  __syncthreads();
  if (tid < 32) {
    float d = Cs[64 + tid][64 + tid];
    rdv[tid] = 1.0f / d;
    lfacc += logf(fabsf(d));
    flacc += (d < 0.f ? 1 : 0) + (d == 0.f ? (1 << 16) : 0);
  }
  __syncthreads();
  {
    int r = tid >> 5, c = tid & 31;
    float acc = 0.f;
    for (int k = 0; k < 32; ++k)
      acc += Cs[96 + r][64 + k] * rdv[k] * Cs[64 + k][96 + c];
    Cs[96 + r][96 + c] -= acc;
  }
  __syncthreads();
  {
    int r5 = tid >> 3, c4 = (tid & 7) * 4;
    for (int j = 0; j < 31; ++j) {
      if (tid < 256 && r5 > j) {
        float inv = 1.0f / Cs[96 + j][96 + j];
        float lrj = Cs[96 + r5][96 + j] * inv;
#pragma unroll
        for (int u = 0; u < 4; ++u) {
          int c = c4 + u;
          if (c > j) Cs[96 + r5][96 + c] -= lrj * Cs[96 + j][96 + c];
        }
      }
      __syncthreads();
    }
    if (tid < 32) {
      float d = Cs[96 + tid][96 + tid];
      lfacc += logf(fabsf(d));
      flacc += (d < 0.f ? 1 : 0) + (d == 0.f ? (1 << 16) : 0);
    }
  }
#pragma unroll
  for (int off = 32; off; off >>= 1) { lfacc += __shfl_down(lfacc, off); flacc += __shfl_down(flacc, off); }
  if (lane == 0) { wsum[w] = lfacc; wflg[w] = flacc; }
  __syncthreads();
  if (tid == 0) {
    float lf = 0.f; int fl = 0;
#pragma unroll
    for (int i = 0; i < 16; ++i) { lf += wsum[i]; fl += wflg[i]; }
    atomicAdd(&slog[b], lf);
    atomicAdd(&negc[b], fl & 0xffff);
    atomicAdd(&zerc[b], fl >> 16);
  }
}

// ---------------- K7: edge reduce + final loss (one 512-thread block) ----------------
__global__ __launch_bounds__(512) void k7_final(const float* __restrict__ edgeval,
    const float* __restrict__ rs, const int* __restrict__ roots,
    const float* __restrict__ slog, const int* __restrict__ negc,
    const int* __restrict__ zerc, float* __restrict__ out) {
  __shared__ float gld[8];
  int w = threadIdx.x >> 6, lane = threadIdx.x & 63;
  float s = 0.f;
  for (int e = lane; e < 1023; e += 64) s += edgeval[w * 1023 + e];
#pragma unroll
  for (int off = 32; off; off >>= 1) s += __shfl_down(s, off);
  if (lane == 0) gld[w] = s;
  __syncthreads();
  if (threadIdx.x == 0) {
    float acc = 0.f;
    for (int b = 0; b < BB; ++b) {
      int root = roots[b];
      float gold = rs[b * NN + root] + gld[b];
      float ld = slog[b];
      bool pos = ((negc[b] & 1) == 0) && (zerc[b] == 0);
      float loss = 0.f;
      if (pos && !isnan(ld) && !isnan(gold)) {
        if (gold <= ld) loss = ld - gold;
      }
      if (isnan(loss) || isinf(loss)) loss = 0.f;
      acc += loss;
    }
    out[0] = ALPHAC * acc / (float)BB;
  }
}

extern "C" void kernel_launch(void* const* d_in, const int* in_sizes, int n_in,
                              void* d_out, int out_size, void* d_ws, size_t ws_size,
                              hipStream_t stream) {
  (void)in_sizes; (void)n_in; (void)out_size; (void)ws_size;
  const float* h_cat  = (const float*)d_in[0];
  const float* left   = (const float*)d_in[1];
  const float* right  = (const float*)d_in[2];
  const int*   roots  = (const int*)d_in[3];
  const float* W_bilin = (const float*)d_in[4];
  const float* b_bilin = (const float*)d_in[5];
  const float* W_head = (const float*)d_in[6];
  const float* W_dep  = (const float*)d_in[7];
  const float* W_r1   = (const float*)d_in[8];
  const float* b_r1   = (const float*)d_in[9];
  const float* W_r2   = (const float*)d_in[10];
  const float* b_r2   = (const float*)d_in[11];

  float* ws = (float*)d_ws;
  unsigned short* tmp_bf = (unsigned short*)(ws + OFF_TMPBF);
  unsigned short* h_bf   = (unsigned short*)(ws + OFF_HBF);
  unsigned short* BT     = (unsigned short*)(ws + OFF_BT);
  unsigned* par  = (unsigned*)(ws + OFF_EL);
  float* edgeval = ws + OFF_EV;
  unsigned short* r1pre  = (unsigned short*)(ws + OFF_R1);
  unsigned short* M = (unsigned short*)(ws + OFF_M);
  float* sm    = ws + OFF_SM;
  float* head0 = sm + O_H0;
  float* head1 = sm + O_H1;
  float* dep0  = sm + O_D0;
  float* dep1  = sm + O_D1;
  float* rs    = sm + O_RS;
  float* gold  = sm + O_GOLD;
  float* slog  = sm + O_SLOG;
  int*   negc  = (int*)(sm + O_NEG);
  int*   zerc  = (int*)(sm + O_ZER);
  float* colsum = sm + O_CS;

  hipMemsetAsync(gold, 0, (32 + BB * NN) * sizeof(float), stream); // gold/slog/negc/zerc/colsum

  kA_pre<<<6912, 256, 0, stream>>>(h_cat, W_bilin, W_r1, W_head, W_dep, left, right,
                                   h_bf, BT, head0, head1, dep0, dep1, par);
  kF<<<256, 1024, 0, stream>>>(h_bf, BT, b_bilin, head0, head1, dep0, dep1,
                               tmp_bf, r1pre, M, colsum);
  kB_post<<<4094, 256, 0, stream>>>(par, tmp_bf, h_bf, head0, head1, dep0, dep1,
                                    b_bilin, r1pre, b_r1, W_r2, b_r2, edgeval, rs);
  k3b_diag<<<8, 1024, 0, stream>>>(M, colsum, rs);
  for (int s = 0; s < 3; ++s) {
    int k0 = s * 256;
    int rem = 1024 - 256 - k0;
    int nt_r = rem / 64, nt_c = rem / 128;
    k6_schur256<<<nt_r * nt_c * 8, 256, 0, stream>>>(M, k0, nt_c, slog, negc, zerc);
  }
  k9_final<<<8, 1024, 0, stream>>>(M, slog, negc, zerc);
  k7_final<<<1, 512, 0, stream>>>(edgeval, rs, roots, slog, negc, zerc, (float*)d_out);
}